// Round 1
// baseline (230.831 us; speedup 1.0000x reference)
//
#include <hip/hip_runtime.h>
#include <math.h>

// Problem constants (from reference): B=8, S=4096, D=1024, H=12.
#define D_DIM 1024
#define S_DIM 4096

// ---------------------------------------------------------------------------
// Kernel 1: compute wave[t] = (1/H) * sum_i amp[i] * sin(2*pi*f[i]*(time + t/S))
// Tiny (S=4096 threads). Done in double so phase (up to ~32564 rad) has no
// fp32 argument-reduction error; wave[] is then exact to ~1 ulp fp32.
// ---------------------------------------------------------------------------
__global__ void ResonanceField_wave_kernel(const float* __restrict__ freq,
                                           const float* __restrict__ amp,
                                           const float* __restrict__ time_p,
                                           float* __restrict__ wave,
                                           int H, int S) {
    int t = blockIdx.x * blockDim.x + threadIdx.x;
    if (t >= S) return;
    double tf = (double)time_p[0] + (double)t / (double)S;
    double acc = 0.0;
    for (int i = 0; i < H; ++i) {
        double phase = (2.0 * M_PI) * (double)freq[i] * tf;
        acc += (double)amp[i] * sin(phase);
    }
    wave[t] = (float)(acc / (double)H);
}

// ---------------------------------------------------------------------------
// Kernel 2: out[b,t,d] = x[b,t,d] * wave[t]
// One block per (b,t) row: 256 threads x float4 = 1024 floats = one row of D.
// t = blockIdx.x % S is block-uniform -> wave[t] is a scalar (s_load) broadcast.
// Pure streaming: 16 B/lane coalesced load + store.
// ---------------------------------------------------------------------------
__global__ void ResonanceField_scale_kernel(const float4* __restrict__ x,
                                            const float* __restrict__ wave,
                                            float4* __restrict__ out) {
    const int t = blockIdx.x & (S_DIM - 1);
    const float w = wave[t];
    const size_t idx = (size_t)blockIdx.x * blockDim.x + threadIdx.x;
    float4 v = x[idx];
    v.x *= w; v.y *= w; v.z *= w; v.w *= w;
    out[idx] = v;
}

// ---------------------------------------------------------------------------
// Fallback (only if ws_size < S*4 bytes): fused, computes the 12-sine sum
// per thread in fp32. Same math order as the numpy ref ((2pi*f) * (time+t/S)).
// ---------------------------------------------------------------------------
__global__ void ResonanceField_fused_kernel(const float4* __restrict__ x,
                                            const float* __restrict__ freq,
                                            const float* __restrict__ amp,
                                            const float* __restrict__ time_p,
                                            float4* __restrict__ out,
                                            int H) {
    const int t = blockIdx.x & (S_DIM - 1);
    const float tf = time_p[0] + (float)t * (1.0f / (float)S_DIM);
    float acc = 0.0f;
    for (int i = 0; i < H; ++i) {
        float c = 6.2831853071795864769f * freq[i];
        acc += amp[i] * sinf(c * tf);
    }
    const float w = acc / (float)H;
    const size_t idx = (size_t)blockIdx.x * blockDim.x + threadIdx.x;
    float4 v = x[idx];
    v.x *= w; v.y *= w; v.z *= w; v.w *= w;
    out[idx] = v;
}

extern "C" void kernel_launch(void* const* d_in, const int* in_sizes, int n_in,
                              void* d_out, int out_size, void* d_ws, size_t ws_size,
                              hipStream_t stream) {
    const float* x    = (const float*)d_in[0];
    const float* freq = (const float*)d_in[1];
    const float* amp  = (const float*)d_in[2];
    const float* time_p = (const float*)d_in[3];
    float* out = (float*)d_out;

    const int H = in_sizes[1];                 // 12
    const long long total = (long long)in_sizes[0];   // B*S*D = 33554432
    const int rows = (int)(total / D_DIM);     // B*S = 32768 blocks
    const int threads = 256;                   // 256 * float4 = 1024 = D

    if (ws_size >= (size_t)S_DIM * sizeof(float)) {
        float* wave = (float*)d_ws;
        ResonanceField_wave_kernel<<<(S_DIM + threads - 1) / threads, threads, 0, stream>>>(
            freq, amp, time_p, wave, H, S_DIM);
        ResonanceField_scale_kernel<<<rows, threads, 0, stream>>>(
            (const float4*)x, wave, (float4*)out);
    } else {
        ResonanceField_fused_kernel<<<rows, threads, 0, stream>>>(
            (const float4*)x, freq, amp, time_p, (float4*)out, H);
    }
}